// Round 12
// baseline (194.732 us; speedup 1.0000x reference)
//
#include <hip/hip_runtime.h>
#include <cstdint>

// Fixed problem shape: B=2, S=2048, D_MODEL=1024, H=16, Dk=64
constexpr int S    = 2048;
constexpr int D    = 1024;
constexpr int NH   = 16;
constexpr int DK   = 64;
constexpr int MTOK = 2 * S;   // B*S = 4096 token rows

typedef __bf16 bf16x8 __attribute__((ext_vector_type(8)));
typedef __bf16 bf16x4 __attribute__((ext_vector_type(4)));
typedef float  floatx4 __attribute__((ext_vector_type(4)));

// R4 lesson: global_load_lds requires lane-monotone global sources; no source swizzle.
__device__ __forceinline__ void async_cp16(const void* g, void* l) {
    __builtin_amdgcn_global_load_lds(
        (const __attribute__((address_space(1))) uint32_t*)g,
        (__attribute__((address_space(3))) uint32_t*)l, 16, 0, 0);
}

// ------------- fused prep: z<4 -> W transpose+cvt; z==4 -> x fp32->bf16 -------------
__global__ __launch_bounds__(256) void cvt_prep(
    const float* __restrict__ x, __bf16* __restrict__ xb,
    const float* __restrict__ W0, const float* __restrict__ W1,
    const float* __restrict__ W2, const float* __restrict__ W3,
    __bf16* __restrict__ T0, __bf16* __restrict__ T1,
    __bf16* __restrict__ T2, __bf16* __restrict__ T3)
{
    const int t = threadIdx.x;
    if (blockIdx.z == 4) {
        int blk = blockIdx.y * 16 + blockIdx.x;
        const float4* src = (const float4*)x;
        #pragma unroll
        for (int ii = 0; ii < 16; ++ii) {
            int idx = blk * 4096 + ii * 256 + t;     // float4 index, coalesced
            float4 v = src[idx];
            bf16x4 o;
            o[0] = (__bf16)v.x; o[1] = (__bf16)v.y; o[2] = (__bf16)v.z; o[3] = (__bf16)v.w;
            *(bf16x4*)&xb[(size_t)idx * 4] = o;
        }
        return;
    }
    const float* W = (blockIdx.z == 0) ? W0 : (blockIdx.z == 1) ? W1 : (blockIdx.z == 2) ? W2 : W3;
    __bf16*      T = (blockIdx.z == 0) ? T0 : (blockIdx.z == 1) ? T1 : (blockIdx.z == 2) ? T2 : T3;
    __shared__ __bf16 tile[64][65];
    const int k0 = blockIdx.y * 64, n0 = blockIdx.x * 64;
    #pragma unroll
    for (int i = 0; i < 4; ++i) {
        int k = (t >> 4) + i * 16;
        int n = (t & 15) * 4;
        float4 v = *(const float4*)&W[(size_t)(k0 + k) * D + n0 + n];
        tile[n + 0][k] = (__bf16)v.x;
        tile[n + 1][k] = (__bf16)v.y;
        tile[n + 2][k] = (__bf16)v.z;
        tile[n + 3][k] = (__bf16)v.w;
    }
    __syncthreads();
    #pragma unroll
    for (int i = 0; i < 4; ++i) {
        int n = (t >> 4) + i * 16;
        int k = (t & 15) * 4;
        bf16x4 o;
        o[0] = tile[n][k]; o[1] = tile[n][k + 1]; o[2] = tile[n][k + 2]; o[3] = tile[n][k + 3];
        *(bf16x4*)&T[(size_t)(n0 + n) * D + k0 + k] = o;
    }
}

// ------------- templated MFMA GEMM core (linear staging, R3 semantics) -------------
constexpr int BM = 128, BK = 64;

template<int JT>
__device__ __forceinline__ void gemm_core(
    const __bf16* __restrict__ A, const __bf16* __restrict__ Bt,
    __bf16* Alds, __bf16* Blds, int m0, int n0, floatx4 (&acc)[4][JT])
{
    const int tid = threadIdx.x;
    const int w = tid >> 6, l = tid & 63;
    const int wm = (w >> 1) * 64, wn = (w & 1) * 16 * JT;
    const int lr = l & 15, lg = l >> 4;

    #pragma unroll
    for (int i = 0; i < 4; ++i)
        #pragma unroll
        for (int j = 0; j < JT; ++j)
            acc[i][j] = (floatx4){0.f, 0.f, 0.f, 0.f};

    for (int k0 = 0; k0 < D; k0 += BK) {
        #pragma unroll
        for (int i = 0; i < 4; ++i) {
            int c = i * 256 + tid, row = c >> 3, g = c & 7;
            async_cp16(&A[(size_t)(m0 + row) * D + k0 + g * 8], &Alds[c * 8]);
        }
        #pragma unroll
        for (int i = 0; i < JT; ++i) {
            int c = i * 256 + tid, row = c >> 3, g = c & 7;
            async_cp16(&Bt[(size_t)(n0 + row) * D + k0 + g * 8], &Blds[c * 8]);
        }
        __syncthreads();
        #pragma unroll
        for (int kk = 0; kk < 2; ++kk) {
            bf16x8 af[4], bfr[JT];
            #pragma unroll
            for (int i = 0; i < 4; ++i)
                af[i] = *(const bf16x8*)&Alds[(wm + i * 16 + lr) * BK + kk * 32 + lg * 8];
            #pragma unroll
            for (int j = 0; j < JT; ++j)
                bfr[j] = *(const bf16x8*)&Blds[(wn + j * 16 + lr) * BK + kk * 32 + lg * 8];
            #pragma unroll
            for (int i = 0; i < 4; ++i)
                #pragma unroll
                for (int j = 0; j < JT; ++j)
                    acc[i][j] = __builtin_amdgcn_mfma_f32_16x16x32_bf16(af[i], bfr[j], acc[i][j], 0, 0, 0);
        }
        __syncthreads();
    }
}

// ------------- fused-A QKV projection: one block -> Q,K,V for its (m,n) tile -------------
// BM=128 tokens x BN=64 dims (one head).  A staged once per k-iter, shared by 3 B-tiles.
// Q/K epilogue: LDS transpose (stride 72 = 144 B, 16B-aligned!) -> contiguous bf16x8 stores.
// V: direct bf16x4 transposed store.  Q scale folds 1/sqrt(Dk) and log2(e).
__global__ __launch_bounds__(256, 2) void gemm_qkv(
    const __bf16* __restrict__ xb,
    const __bf16* __restrict__ WqT, const __bf16* __restrict__ WkT, const __bf16* __restrict__ WvT,
    const float* __restrict__ bq, const float* __restrict__ bk, const float* __restrict__ bv,
    __bf16* __restrict__ Qb, __bf16* __restrict__ Kb, __bf16* __restrict__ Vt)
{
    __shared__ __align__(16) char smem[40960];
    __bf16* Alds = (__bf16*)smem;                  // [128][64]  16 KB
    __bf16* Blds = (__bf16*)(smem + 16384);        // [3][64][64] 24 KB
    __bf16* Tep  = (__bf16*)smem;                  // epilogue transpose [128][72] 18.4 KB (reuse)

    const int tid = threadIdx.x;
    const int w = tid >> 6, l = tid & 63;
    const int wm = (w >> 1) * 64, wn = (w & 1) * 32;
    const int lr = l & 15, lg = l >> 4;
    const int m0 = blockIdx.y * BM, n0 = blockIdx.x * 64;

    floatx4 acc[3][4][2];
    #pragma unroll
    for (int z = 0; z < 3; ++z)
        #pragma unroll
        for (int i = 0; i < 4; ++i)
            #pragma unroll
            for (int j = 0; j < 2; ++j)
                acc[z][i][j] = (floatx4){0.f, 0.f, 0.f, 0.f};

    const __bf16* Wz[3] = {WqT, WkT, WvT};

    for (int k0 = 0; k0 < D; k0 += BK) {
        #pragma unroll
        for (int i = 0; i < 4; ++i) {            // A: 1024 granules (128 rows x 8)
            int c = i * 256 + tid, row = c >> 3, g = c & 7;
            async_cp16(&xb[(size_t)(m0 + row) * D + k0 + g * 8], &Alds[c * 8]);
        }
        #pragma unroll
        for (int z = 0; z < 3; ++z)
            #pragma unroll
            for (int i = 0; i < 2; ++i) {        // B[z]: 512 granules (64 rows x 8)
                int c = i * 256 + tid, row = c >> 3, g = c & 7;
                async_cp16(&Wz[z][(size_t)(n0 + row) * D + k0 + g * 8],
                           &Blds[(z * 4096) + c * 8]);
            }
        __syncthreads();
        #pragma unroll
        for (int kk = 0; kk < 2; ++kk) {
            bf16x8 af[4];
            #pragma unroll
            for (int i = 0; i < 4; ++i)
                af[i] = *(const bf16x8*)&Alds[(wm + i * 16 + lr) * BK + kk * 32 + lg * 8];
            #pragma unroll
            for (int z = 0; z < 3; ++z) {
                bf16x8 bfr[2];
                #pragma unroll
                for (int j = 0; j < 2; ++j)
                    bfr[j] = *(const bf16x8*)&Blds[z * 4096 + (wn + j * 16 + lr) * BK + kk * 32 + lg * 8];
                #pragma unroll
                for (int i = 0; i < 4; ++i)
                    #pragma unroll
                    for (int j = 0; j < 2; ++j)
                        acc[z][i][j] = __builtin_amdgcn_mfma_f32_16x16x32_bf16(af[i], bfr[j], acc[z][i][j], 0, 0, 0);
            }
        }
        __syncthreads();
    }

    const int b = m0 >> 11, h = n0 >> 6;
    const int row = tid >> 1, half = tid & 1;    // epilogue read/store mapping

    // ---- V: direct transposed store (bf16x4 along s), h fixed per block ----
    #pragma unroll
    for (int i = 0; i < 4; ++i)
        #pragma unroll
        for (int j = 0; j < 2; ++j) {
            int n = n0 + wn + j * 16 + lr;
            int m = m0 + wm + i * 16 + lg * 4;
            float bn = bv[n];
            bf16x4 o;
            #pragma unroll
            for (int r = 0; r < 4; ++r) o[r] = (__bf16)(acc[2][i][j][r] + bn);
            size_t off = ((size_t)(b * NH + h) * DK + (n & (DK - 1))) * S + (m & (S - 1));
            *(bf16x4*)&Vt[off] = o;
        }

    // ---- Q then K: LDS transpose -> contiguous stores ----
    #pragma unroll
    for (int z = 0; z < 2; ++z) {
        const float* bias = (z == 0) ? bq : bk;
        const float scale = (z == 0) ? 0.18033688f : 1.0f;   // 0.125 * log2(e)
        __bf16* Out = (z == 0) ? Qb : Kb;
        __syncthreads();                        // Tep region free (k-loop or prev z done)
        #pragma unroll
        for (int i = 0; i < 4; ++i)
            #pragma unroll
            for (int j = 0; j < 2; ++j) {
                int nl = wn + j * 16 + lr;
                float bn = bias[n0 + nl];
                #pragma unroll
                for (int r = 0; r < 4; ++r) {
                    int ml = wm + i * 16 + lg * 4 + r;
                    Tep[ml * 72 + nl] = (__bf16)((acc[z][i][j][r] + bn) * scale);
                }
            }
        __syncthreads();
        // thread -> (row, half): 32 contiguous dims of one token; wave covers 32
        // consecutive tokens x 128 B contiguous in Qb/Kb ([bh][s_local][dk] layout).
        int s_local = (m0 + row) & (S - 1);     // R11 bug fix: mask to local s!
        __bf16* op = Out + ((size_t)(b * NH + h) * S + s_local) * DK + half * 32;
        #pragma unroll
        for (int c = 0; c < 4; ++c)
            *(bf16x8*)&op[c * 8] = *(const bf16x8*)&Tep[row * 72 + half * 32 + c * 8];
    }
}

// ------------- output projection (128x64 tiles): fp32 row-major [M][D] -------------
__global__ __launch_bounds__(256, 2) void gemm_out(
    const __bf16* __restrict__ A, const __bf16* __restrict__ Bt,
    const float* __restrict__ bias, float* __restrict__ Cout)
{
    __shared__ __align__(16) __bf16 Alds[BM * BK];
    __shared__ __align__(16) __bf16 Blds[64 * BK];
    const int m0 = blockIdx.y * BM, n0 = blockIdx.x * 64;

    floatx4 acc[4][2];
    gemm_core<2>(A, Bt, Alds, Blds, m0, n0, acc);

    const int tid = threadIdx.x;
    const int w = tid >> 6, l = tid & 63;
    const int wm = (w >> 1) * 64, wn = (w & 1) * 32;
    const int lr = l & 15, lg = l >> 4;
    #pragma unroll
    for (int i = 0; i < 4; ++i)
        #pragma unroll
        for (int j = 0; j < 2; ++j) {
            int n = n0 + wn + j * 16 + lr;
            #pragma unroll
            for (int r = 0; r < 4; ++r) {
                int m = m0 + wm + i * 16 + lg * 4 + r;
                Cout[(size_t)m * D + n] = acc[i][j][r] + bias[n];
            }
        }
}

// ------------- MFMA flash attention (R10-validated, verbatim) -------------
constexpr int QT = 128;   // queries per block (32 per wave)
constexpr int KT = 64;    // keys per tile
constexpr float SOFTMAX_C2 = 14.4269504f;   // 10 * log2(e)

__global__ __launch_bounds__(256, 2) void attn_mfma(
    const __bf16* __restrict__ Q, const __bf16* __restrict__ K,
    const __bf16* __restrict__ Vt, __bf16* __restrict__ O)
{
    __shared__ __align__(16) __bf16 Klds[2][KT * DK];   // [buf][key][dk], swizzled
    __shared__ __align__(16) __bf16 Vlds[2][DK * KT];   // [buf][dk][key], swizzled
    __shared__ __align__(16) __bf16 Plds[4][32 * 64];   // per-wave, XOR-swizzled [q][key]

    const int tid = threadIdx.x;
    const int w = tid >> 6, l = tid & 63;
    const int lr = l & 15, lg = l >> 4;
    const int sw = lr & 7;
    const int bh = blockIdx.y;
    const int q0 = blockIdx.x * QT;
    const __bf16* Kbase = K  + (size_t)bh * S * DK;
    const __bf16* Vbase = Vt + (size_t)bh * DK * S;

    bf16x8 qf[2][2];
    {
        const __bf16* qp = Q + ((size_t)bh * S + q0 + w * 32) * DK;
        #pragma unroll
        for (int i = 0; i < 2; ++i)
            #pragma unroll
            for (int kk = 0; kk < 2; ++kk)
                qf[i][kk] = *(const bf16x8*)&qp[(i * 16 + lr) * DK + kk * 32 + lg * 8];
    }
    bf16x8 vones;
    #pragma unroll
    for (int j = 0; j < 8; ++j) vones[j] = (__bf16)1.0f;

    floatx4 acc[4][2];
    #pragma unroll
    for (int jd = 0; jd < 4; ++jd)
        #pragma unroll
        for (int i = 0; i < 2; ++i)
            acc[jd][i] = (floatx4){0.f, 0.f, 0.f, 0.f};
    floatx4 psacc[2];
    psacc[0] = (floatx4){0.f, 0.f, 0.f, 0.f};
    psacc[1] = (floatx4){0.f, 0.f, 0.f, 0.f};

    bf16x8 kreg[2], vreg[2];
    auto gload = [&](int t0) {
        #pragma unroll
        for (int ii = 0; ii < 2; ++ii) {
            int c = ii * 256 + tid, row = c >> 3, g = c & 7;
            kreg[ii] = *(const bf16x8*)&Kbase[(size_t)(t0 + row) * DK + g * 8];
            vreg[ii] = *(const bf16x8*)&Vbase[(size_t)row * S + t0 + g * 8];
        }
    };
    auto lwrite = [&](int buf) {
        #pragma unroll
        for (int ii = 0; ii < 2; ++ii) {
            int c = ii * 256 + tid, row = c >> 3, gs = (c & 7) ^ (row & 7);
            *(bf16x8*)&Klds[buf][row * 64 + gs * 8] = kreg[ii];
            *(bf16x8*)&Vlds[buf][row * 64 + gs * 8] = vreg[ii];
        }
    };

    gload(0);
    lwrite(0);
    gload(KT);

    for (int t0 = 0; t0 < S; t0 += KT) {
        const int cur = (t0 >> 6) & 1;
        __syncthreads();

        floatx4 sa[4][2];
        #pragma unroll
        for (int j = 0; j < 4; ++j)
            #pragma unroll
            for (int i = 0; i < 2; ++i)
                sa[j][i] = (floatx4){0.f, 0.f, 0.f, 0.f};
        #pragma unroll
        for (int kk = 0; kk < 2; ++kk) {
            bf16x8 kf[4];
            #pragma unroll
            for (int j = 0; j < 4; ++j)
                kf[j] = *(const bf16x8*)&Klds[cur][(j * 16 + lr) * DK + (((kk * 4 + lg) ^ sw) * 8)];
            #pragma unroll
            for (int j = 0; j < 4; ++j)
                #pragma unroll
                for (int i = 0; i < 2; ++i)
                    sa[j][i] = __builtin_amdgcn_mfma_f32_16x16x32_bf16(kf[j], qf[i][kk], sa[j][i], 0, 0, 0);
        }

        #pragma unroll
        for (int j = 0; j < 4; ++j)
            #pragma unroll
            for (int i = 0; i < 2; ++i) {
                bf16x4 pb;
                #pragma unroll
                for (int r = 0; r < 4; ++r)
                    pb[r] = (__bf16)__builtin_amdgcn_exp2f(sa[j][i][r] - SOFTMAX_C2);
                int gsw = (j * 2 + (lg >> 1)) ^ sw;
                *(bf16x4*)&Plds[w][(i * 16 + lr) * 64 + gsw * 8 + (lg & 1) * 4] = pb;
            }

        #pragma unroll
        for (int kk = 0; kk < 2; ++kk) {
            bf16x8 vf[4], pf[2];
            #pragma unroll
            for (int i = 0; i < 2; ++i) {
                int gsw = (kk * 4 + lg) ^ sw;
                pf[i] = *(const bf16x8*)&Plds[w][(i * 16 + lr) * 64 + gsw * 8];
            }
            #pragma unroll
            for (int jd = 0; jd < 4; ++jd)
                vf[jd] = *(const bf16x8*)&Vlds[cur][(jd * 16 + lr) * KT + (((kk * 4 + lg) ^ sw) * 8)];
            #pragma unroll
            for (int jd = 0; jd < 4; ++jd)
                #pragma unroll
                for (int i = 0; i < 2; ++i)
                    acc[jd][i] = __builtin_amdgcn_mfma_f32_16x16x32_bf16(vf[jd], pf[i], acc[jd][i], 0, 0, 0);
            #pragma unroll
            for (int i = 0; i < 2; ++i)
                psacc[i] = __builtin_amdgcn_mfma_f32_16x16x32_bf16(vones, pf[i], psacc[i], 0, 0, 0);
        }

        if (t0 + KT < S) {
            lwrite(cur ^ 1);
            if (t0 + 2 * KT < S) gload(t0 + 2 * KT);
        }
    }

    const int b = bh >> 4, h = bh & 15;
    #pragma unroll
    for (int i = 0; i < 2; ++i) {
        float inv = 1.f / psacc[i][0];
        int q = q0 + w * 32 + i * 16 + lr;
        __bf16* op = O + (size_t)(b * S + q) * D + h * DK;
        #pragma unroll
        for (int jd = 0; jd < 4; ++jd) {
            bf16x4 ov;
            #pragma unroll
            for (int r = 0; r < 4; ++r) ov[r] = (__bf16)(acc[jd][i][r] * inv);
            *(bf16x4*)&op[jd * 16 + lg * 4] = ov;
        }
    }
}

extern "C" void kernel_launch(void* const* d_in, const int* in_sizes, int n_in,
                              void* d_out, int out_size, void* d_ws, size_t ws_size,
                              hipStream_t stream) {
    const float* x  = (const float*)d_in[0];
    const float* Wq = (const float*)d_in[1];
    const float* bq = (const float*)d_in[2];
    const float* Wk = (const float*)d_in[3];
    const float* bk = (const float*)d_in[4];
    const float* Wv = (const float*)d_in[5];
    const float* bv = (const float*)d_in[6];
    const float* Wo = (const float*)d_in[7];
    const float* bo = (const float*)d_in[8];

    char* ws = (char*)d_ws;
    __bf16* xb  = (__bf16*)(ws);                 // 8 MB  bf16 x [4096][1024]
    __bf16* WqT = (__bf16*)(ws + (8ull  << 20));
    __bf16* WkT = (__bf16*)(ws + (10ull << 20));
    __bf16* WvT = (__bf16*)(ws + (12ull << 20));
    __bf16* WoT = (__bf16*)(ws + (14ull << 20));
    __bf16* Qb  = (__bf16*)(ws + (16ull << 20)); // [BH][S][DK], pre-scaled 0.125*log2e
    __bf16* Kb  = (__bf16*)(ws + (24ull << 20)); // [BH][S][DK]
    __bf16* Vt  = (__bf16*)(ws + (32ull << 20)); // [BH][DK][S]
    __bf16* Ob  = (__bf16*)(ws + (40ull << 20)); // attn out [B*S][D]

    cvt_prep<<<dim3(16, 16, 5), 256, 0, stream>>>(
        x, xb, Wq, Wk, Wv, Wo, WqT, WkT, WvT, WoT);

    gemm_qkv<<<dim3(D / 64, MTOK / BM), 256, 0, stream>>>(
        xb, WqT, WkT, WvT, bq, bk, bv, Qb, Kb, Vt);

    attn_mfma<<<dim3(S / QT, 2 * NH), 256, 0, stream>>>(Qb, Kb, Vt, Ob);

    gemm_out<<<dim3(D / 64, MTOK / BM), 256, 0, stream>>>(Ob, WoT, bo, (float*)d_out);
}